// Round 16
// baseline (263.102 us; speedup 1.0000x reference)
//
#include <hip/hip_runtime.h>
#include <hip/hip_bf16.h>
#include <hip/hip_cooperative_groups.h>

namespace cg = cooperative_groups;

#define NROWS 16384
#define DIM   256
#define DB    (DIM / 2)               // 128 bytes per fp4 row
#define SEGS  6
#define BN    128                     // staged tile: 128 cols x 256 k (fp4) = 16 KB
#define TB    (BN * DB)               // 16384 bytes per staged tile
#define INVT  14.285714285714286f
#define C1f   20.60992915555662f      // log2(e)/0.07 ; A is pre-scaled by this
#define LN2f  0.6931471805599453f

typedef __attribute__((ext_vector_type(8)))  int   int8v;    // MFMA operand (fp4 uses low 4 regs)
typedef __attribute__((ext_vector_type(16))) float f32x16;   // 32x32 MFMA accumulator

#define SCA 0x7F7F7F7Fu   // E8M0 = 2^0   (A scale; A pre-scaled by C1, sigma~1.29)
#define SCB 0x7B7B7B7Bu   // E8M0 = 2^-4  (B scale; B pre-multiplied by 16, sigma~1.0)

// fp4 e2m1 RNE quantize: codes 0..7 = {0, .5, 1, 1.5, 2, 3, 4, 6} (monotonic), bit3 = sign
__device__ __forceinline__ unsigned fp4q(float v) {
    float a = fabsf(v);
    unsigned s = (__float_as_uint(v) >> 28) & 0x8u;
    unsigned idx = (unsigned)(a >= 0.25f) + (a >= 0.75f) + (a >= 1.25f) + (a >= 1.75f)
                 + (a >= 2.5f) + (a >= 3.5f) + (a >= 5.0f);
    return s | idx;
}

// ---- shared device helpers (used by both fused and fallback paths) ----

__device__ __forceinline__ void norm_row(
    const float* __restrict__ fl, const float* __restrict__ fg,
    unsigned char* __restrict__ A, unsigned char* __restrict__ B,
    float* __restrict__ diag, int row, int lane)
{
    float4 xl = ((const float4*)(fl + (size_t)row * DIM))[lane];
    float4 xg = ((const float4*)(fg + (size_t)row * DIM))[lane];
    float ssl = xl.x*xl.x + xl.y*xl.y + xl.z*xl.z + xl.w*xl.w;
    float ssg = xg.x*xg.x + xg.y*xg.y + xg.z*xg.z + xg.w*xg.w;
    for (int m = 1; m < 64; m <<= 1) {
        ssl += __shfl_xor(ssl, m, 64);
        ssg += __shfl_xor(ssg, m, 64);
    }
    float il = 1.0f / fmaxf(sqrtf(ssl), 1e-12f);
    float ig = 1.0f / fmaxf(sqrtf(ssg), 1e-12f);
    float nl0 = xl.x*il, nl1 = xl.y*il, nl2 = xl.z*il, nl3 = xl.w*il;
    float ng0 = xg.x*ig, ng1 = xg.y*ig, ng2 = xg.z*ig, ng3 = xg.w*ig;

    unsigned pa4 = fp4q(nl0 * C1f) | (fp4q(nl1 * C1f) << 4)
                 | (fp4q(nl2 * C1f) << 8) | (fp4q(nl3 * C1f) << 12);
    ((unsigned short*)(A + (size_t)row * DB))[lane] = (unsigned short)pa4;

    unsigned pb4 = fp4q(ng0 * 16.0f) | (fp4q(ng1 * 16.0f) << 4)
                 | (fp4q(ng2 * 16.0f) << 8) | (fp4q(ng3 * 16.0f) << 12);
    int kcb4 = lane >> 3;
    unsigned chunk = (unsigned)((row >> 7) * 1024 + ((row >> 6) & 1) * 512
                                + kcb4 * 64 + (row & 63));
    ((unsigned short*)B)[chunk * 8 + (lane & 7)] = (unsigned short)pb4;

    float d = nl0*ng0 + nl1*ng1 + nl2*ng2 + nl3*ng3;
    for (int m = 1; m < 64; m <<= 1) d += __shfl_xor(d, m, 64);
    if (lane == 0) diag[row] = d;
}

#define MFMA4(dst, a, b, cin) \
    dst = __builtin_amdgcn_mfma_scale_f32_32x32x64_f8f6f4(a, b, cin, 4, 4, 0, SCA, 0, SCB)

// R29 sim phase body (zero-spill 2-chain column-pair interleave), shared.
__device__ __forceinline__ void sim_phase(
    const unsigned char* __restrict__ A, const unsigned char* __restrict__ B,
    float* __restrict__ lpart, unsigned char* bt,
    int tid, int segX, int blkY)
{
    int lane = tid & 63;
    int l31  = lane & 31, half = lane >> 5;
    int wave = tid >> 6;
    int seg  = segX;                              // 0..5
    int nt   = 21 + (seg < 2 ? 1 : 0);            // tiles this seg
    int T0   = seg * 21 + (seg < 2 ? seg : 2);    // first tile
    int rowBase = blkY * 128 + wave * 32;         // 32 rows per wave

    unsigned vb = (unsigned)(l31 * 16 + half * 1024);
    const int4 zero4 = make_int4(0, 0, 0, 0);

    int8v af[4];
    {
        const unsigned char* ap = A + (size_t)(rowBase + l31) * DB + half * 16;
#pragma unroll
        for (int kk = 0; kk < 4; ++kk) {
            ((int4*)&af[kk])[0] = *(const int4*)(ap + kk * 32);
            ((int4*)&af[kk])[1] = zero4;
        }
    }

    f32x16 lv;
    f32x16 p0, p1, q0, q1;
#pragma unroll
    for (int r = 0; r < 16; ++r) {
        lv[r] = -2.0f;     // compensate the one dummy pair-epilogue
        q0[r] = 0.0f; q1[r] = 0.0f;
    }

    auto stage = [&](int T, unsigned bufo) {
        const unsigned char* g = B + (size_t)T * TB + (unsigned)tid * 16;
        unsigned lo = bufo + (unsigned)tid * 16;
#pragma unroll
        for (int j = 0; j < 4; ++j) {
            __builtin_amdgcn_global_load_lds(
                (const __attribute__((address_space(1))) unsigned int*)(g + j * 4096),
                (__attribute__((address_space(3))) unsigned int*)&bt[lo + j * 4096],
                16, 0, 0);
        }
    };

    auto slot = [&](f32x16& c0, f32x16& c1, f32x16& e0, f32x16& e1,
                    unsigned ab, unsigned offA, unsigned offB) {
#pragma unroll
        for (int r = 0; r < 16; ++r) { c0[r] = 0.0f; c1[r] = 0.0f; }
        int8v b0, b1, b2, b3;
        ((int4*)&b0)[1] = zero4; ((int4*)&b1)[1] = zero4;
        ((int4*)&b2)[1] = zero4; ((int4*)&b3)[1] = zero4;
        ((int4*)&b0)[0] = *(const int4*)&bt[ab + offA];            // chain0 kk=0
        ((int4*)&b1)[0] = *(const int4*)&bt[ab + offB];            // chain1 kk=0
        MFMA4(c0, af[0], b0, c0);
        MFMA4(c1, af[0], b1, c1);
#pragma unroll
        for (int r = 0; r < 8; ++r)  lv[r] += __builtin_amdgcn_exp2f(e0[r]);
        ((int4*)&b2)[0] = *(const int4*)&bt[ab + offA + 2048u];    // kk=1
        ((int4*)&b3)[0] = *(const int4*)&bt[ab + offB + 2048u];
        MFMA4(c0, af[1], b2, c0);
        MFMA4(c1, af[1], b3, c1);
#pragma unroll
        for (int r = 8; r < 16; ++r) lv[r] += __builtin_amdgcn_exp2f(e0[r]);
        ((int4*)&b0)[0] = *(const int4*)&bt[ab + offA + 4096u];    // kk=2
        ((int4*)&b1)[0] = *(const int4*)&bt[ab + offB + 4096u];
        MFMA4(c0, af[2], b0, c0);
        MFMA4(c1, af[2], b1, c1);
#pragma unroll
        for (int r = 0; r < 8; ++r)  lv[r] += __builtin_amdgcn_exp2f(e1[r]);
        ((int4*)&b2)[0] = *(const int4*)&bt[ab + offA + 6144u];    // kk=3
        ((int4*)&b3)[0] = *(const int4*)&bt[ab + offB + 6144u];
        MFMA4(c0, af[3], b2, c0);
        MFMA4(c1, af[3], b3, c1);
#pragma unroll
        for (int r = 8; r < 16; ++r) lv[r] += __builtin_amdgcn_exp2f(e1[r]);
    };

    stage(T0, 0);

    for (int t = 0; t < nt; ++t) {
        unsigned bufo = (t & 1) ? (unsigned)TB : 0u;
        __syncthreads();   // drains own tile-t DMA, syncs block

        if (t + 1 < nt)
            stage(T0 + t + 1, (t & 1) ? 0u : (unsigned)TB);

        unsigned ab = vb + bufo;
        slot(p0, p1, q0, q1, ab, 0u,    512u);    // cols 0-63,   exp prev pair
        slot(q0, q1, p0, p1, ab, 8192u, 8704u);   // cols 64-127, exp pair just done
    }
#pragma unroll
    for (int r = 0; r < 16; ++r)
        lv[r] += __builtin_amdgcn_exp2f(q0[r]) + __builtin_amdgcn_exp2f(q1[r]);

#pragma unroll
    for (int r = 0; r < 16; ++r) {
        float v = lv[r];
        v += __shfl_xor(v, 1, 64);
        v += __shfl_xor(v, 2, 64);
        v += __shfl_xor(v, 4, 64);
        v += __shfl_xor(v, 8, 64);
        v += __shfl_xor(v, 16, 64);
        lv[r] = v;
    }
    if (l31 == 0) {
#pragma unroll
        for (int r = 0; r < 16; ++r) {
            int row = rowBase + (r & 3) + 8*(r >> 2) + 4*half;
            lpart[(size_t)seg * NROWS + row] = lv[r];
        }
    }
}

// ---- R30/R31: ONE cooperative kernel — norm -> grid.sync -> sim -> grid.sync ->
// reduce. Rationale: across 5 profiled runs, total - sim_lse = 71-77 us, while
// the roofline for norm (37.5 MB ~ 6 us) + reduce (trivial) is 10-15 us: ~50 us
// of kernel-boundary overhead — bigger than any remaining sim-internal lever
// (sim plateaued at ~50 us across occupancy/chain/staging variations; MfmaUtil
// 25-26). Sim phase byte-identical to R29's zero-spill config (768 blocks =
// 3/CU exactly co-resident, 32 KB LDS, ~148 regs). Grid-sync provides the
// device-scope fence for the A/B/diag handoff (G16). Any total-time delta
// attributes to the removed kernel boundaries. If cooperative launch errors,
// kernel_launch falls back to the measured R29 3-launch pipeline (122.8 us).
__global__ __launch_bounds__(256, 3) void fused_kernel(
    const float* __restrict__ fl, const float* __restrict__ fg,
    unsigned char* __restrict__ A, unsigned char* __restrict__ B,
    float* __restrict__ diag, float* __restrict__ lpart,
    float* __restrict__ out)
{
    __shared__ __align__(16) unsigned char bt[2 * TB];   // 2 x 16 KB double buffer (sim phase)

    int tid  = threadIdx.x;
    int lane = tid & 63;
    int wave = tid >> 6;
    int bid  = blockIdx.y * gridDim.x + blockIdx.x;      // 0..767

    // Phase 1: normalize + quantize + diagonal
    {
        int gw = bid * 4 + wave;                         // 0..3071 global wave id
        for (int row = gw; row < NROWS; row += 3072)
            norm_row(fl, fg, A, B, diag, row, lane);
    }

    cg::this_grid().sync();

    if (bid == 0 && tid == 0) out[0] = 0.0f;   // visible to phase 3 via second sync

    // Phase 2: sim-GEMM + fixed-max sumexp (R29 body)
    sim_phase(A, B, lpart, bt, tid, blockIdx.x, blockIdx.y);

    cg::this_grid().sync();

    // Phase 3: final reduce (blocks 0..63, one row per thread)
    if (bid < 64) {
        int row = bid * 256 + tid;
        float t = 0.0f;
#pragma unroll
        for (int g = 0; g < SEGS; ++g) t += lpart[(size_t)g * NROWS + row];
        float s = LN2f * log2f(t) - INVT * diag[row];
        for (int m = 1; m < 64; m <<= 1) s += __shfl_xor(s, m, 64);
        if (lane == 0) atomicAdd(out, s * (1.0f / NROWS));
    }
}

// ---- Fallback path: the measured R29 3-launch pipeline (122.8 us) ----

__global__ __launch_bounds__(256) void norm_diag_kernel(
    const float* __restrict__ fl, const float* __restrict__ fg,
    unsigned char* __restrict__ A, unsigned char* __restrict__ B,
    float* __restrict__ diag, float* __restrict__ out)
{
    int tid  = threadIdx.x;
    int wave = tid >> 6, lane = tid & 63;
    int row  = blockIdx.x * 4 + wave;
    if (blockIdx.x == 0 && tid == 0) out[0] = 0.0f;
    norm_row(fl, fg, A, B, diag, row, lane);
}

__global__ __launch_bounds__(256, 3) void sim_lse_kernel(
    const unsigned char* __restrict__ A, const unsigned char* __restrict__ B,
    float* __restrict__ lpart)
{
    __shared__ __align__(16) unsigned char bt[2 * TB];
    sim_phase(A, B, lpart, bt, threadIdx.x, blockIdx.x, blockIdx.y);
}

__global__ __launch_bounds__(256) void reduce_kernel(
    const float* __restrict__ lpart, const float* __restrict__ diag,
    float* __restrict__ out)
{
    __shared__ float sm[4];
    int gtid = blockIdx.x * 256 + threadIdx.x;
    float s = 0.0f;
    for (int row = gtid; row < NROWS; row += 32 * 256) {
        float t = 0.0f;
#pragma unroll
        for (int g = 0; g < SEGS; ++g) t += lpart[(size_t)g * NROWS + row];
        s += LN2f * log2f(t) - INVT * diag[row];
    }
    for (int m = 1; m < 64; m <<= 1) s += __shfl_xor(s, m, 64);
    int wave = threadIdx.x >> 6, lane = threadIdx.x & 63;
    if (lane == 0) sm[wave] = s;
    __syncthreads();
    if (threadIdx.x == 0) {
        float tot = sm[0] + sm[1] + sm[2] + sm[3];
        atomicAdd(out, tot * (1.0f / NROWS));
    }
}

extern "C" void kernel_launch(void* const* d_in, const int* in_sizes, int n_in,
                              void* d_out, int out_size, void* d_ws, size_t ws_size,
                              hipStream_t stream) {
    const float* fl = (const float*)d_in[0];
    const float* fg = (const float*)d_in[1];
    float* out = (float*)d_out;

    char* ws = (char*)d_ws;
    unsigned char* A = (unsigned char*)ws;                         // 16384*128 = 2 MB (fp4)
    unsigned char* B = A + (size_t)NROWS * DB;                     // 2 MB (fp4, staging layout)
    float* diag  = (float*)(ws + 2 * (size_t)NROWS * DB);          // 64 KB
    float* lpart = diag + NROWS;                                   // SEGS*N*4 = 384 KB

    void* args[] = { (void*)&fl, (void*)&fg, (void*)&A, (void*)&B,
                     (void*)&diag, (void*)&lpart, (void*)&out };
    hipError_t err = hipLaunchCooperativeKernel((const void*)fused_kernel,
                                                dim3(SEGS, NROWS / 128), dim3(256),
                                                args, 0, stream);
    if (err != hipSuccess) {
        // Fallback: measured R29 3-launch pipeline.
        norm_diag_kernel<<<NROWS / 4, 256, 0, stream>>>(fl, fg, A, B, diag, out);
        sim_lse_kernel<<<dim3(SEGS, NROWS / 128), 256, 0, stream>>>(A, B, lpart);
        reduce_kernel<<<32, 256, 0, stream>>>(lpart, diag, out);
    }
}

// Round 19
// 124.075 us; speedup vs baseline: 2.1205x; 2.1205x over previous
//
#include <hip/hip_runtime.h>
#include <hip/hip_bf16.h>

#define NROWS 16384
#define DIM   256
#define DB    (DIM / 2)               // 128 bytes per fp4 row
#define SEGS  6
#define BN    128                     // staged tile: 128 cols x 256 k (fp4) = 16 KB
#define TB    (BN * DB)               // 16384 bytes per staged tile
#define INVT  14.285714285714286f
#define C1f   20.60992915555662f      // log2(e)/0.07 ; A is pre-scaled by this
#define LN2f  0.6931471805599453f

typedef __attribute__((ext_vector_type(8)))  int   int8v;    // MFMA operand (fp4 uses low 4 regs)
typedef __attribute__((ext_vector_type(16))) float f32x16;   // 32x32 MFMA accumulator

#define SCA 0x7F7F7F7Fu   // E8M0 = 2^0   (A scale; A pre-scaled by C1, sigma~1.29)
#define SCB 0x7B7B7B7Bu   // E8M0 = 2^-4  (B scale; B pre-multiplied by 16, sigma~1.0)

// fp4 e2m1 RNE quantize: codes 0..7 = {0, .5, 1, 1.5, 2, 3, 4, 6} (monotonic), bit3 = sign
__device__ __forceinline__ unsigned fp4q(float v) {
    float a = fabsf(v);
    unsigned s = (__float_as_uint(v) >> 28) & 0x8u;
    unsigned idx = (unsigned)(a >= 0.25f) + (a >= 0.75f) + (a >= 1.25f) + (a >= 1.75f)
                 + (a >= 2.5f) + (a >= 3.5f) + (a >= 5.0f);
    return s | idx;
}

// Kernel 1: L2-normalize (fp32); emit fp4 A (row-major, xC1) and fp4 B (x16) in the
// DMA staging layout, plus exact fp32 diagonal. One wave per row.
__global__ __launch_bounds__(256) void norm_diag_kernel(
    const float* __restrict__ fl, const float* __restrict__ fg,
    unsigned char* __restrict__ A, unsigned char* __restrict__ B,
    float* __restrict__ diag, float* __restrict__ out)
{
    int tid  = threadIdx.x;
    int wave = tid >> 6, lane = tid & 63;
    int row  = blockIdx.x * 4 + wave;
    if (blockIdx.x == 0 && tid == 0) out[0] = 0.0f;   // zero accumulator for final atomicAdd

    float4 xl = ((const float4*)(fl + (size_t)row * DIM))[lane];
    float4 xg = ((const float4*)(fg + (size_t)row * DIM))[lane];
    float ssl = xl.x*xl.x + xl.y*xl.y + xl.z*xl.z + xl.w*xl.w;
    float ssg = xg.x*xg.x + xg.y*xg.y + xg.z*xg.z + xg.w*xg.w;
    for (int m = 1; m < 64; m <<= 1) {
        ssl += __shfl_xor(ssl, m, 64);
        ssg += __shfl_xor(ssg, m, 64);
    }
    float il = 1.0f / fmaxf(sqrtf(ssl), 1e-12f);
    float ig = 1.0f / fmaxf(sqrtf(ssg), 1e-12f);
    float nl0 = xl.x*il, nl1 = xl.y*il, nl2 = xl.z*il, nl3 = xl.w*il;
    float ng0 = xg.x*ig, ng1 = xg.y*ig, ng2 = xg.z*ig, ng3 = xg.w*ig;

    unsigned pa4 = fp4q(nl0 * C1f) | (fp4q(nl1 * C1f) << 4)
                 | (fp4q(nl2 * C1f) << 8) | (fp4q(nl3 * C1f) << 12);
    ((unsigned short*)(A + (size_t)row * DB))[lane] = (unsigned short)pa4;

    unsigned pb4 = fp4q(ng0 * 16.0f) | (fp4q(ng1 * 16.0f) << 4)
                 | (fp4q(ng2 * 16.0f) << 8) | (fp4q(ng3 * 16.0f) << 12);
    {
        int kcb4 = lane >> 3;         // 16B chunk along K (0..7)
        unsigned chunk = (unsigned)((row >> 7) * 1024 + ((row >> 6) & 1) * 512
                                    + kcb4 * 64 + (row & 63));
        ((unsigned short*)B)[chunk * 8 + (lane & 7)] = (unsigned short)pb4;
    }

    float d = nl0*ng0 + nl1*ng1 + nl2*ng2 + nl3*ng3;   // exact fp32 diagonal
    for (int m = 1; m < 64; m <<= 1) d += __shfl_xor(d, m, 64);
    if (lane == 0) diag[row] = d;
}

// Kernel 2: fused sim-GEMM + fixed-max sumexp, MX-fp4 32x32x64.
// R32 (resubmitted; broker timeouts) = R29 (measured session best: sim 50.0 us,
// total 122.8) + Z-const cin. Post-mortem R30/R31: cooperative fusion added
// ~146 us on-device (grid-sync spin across 768 blocks / 8 non-coherent L2s +
// low-parallelism norm phase); totals decompose as sim + ~8 us (norm+reduce at
// roofline) + ~65 us HARNESS-FIXED overhead -> the controllable budget is sim
// itself. This revision removes the 64 per-unit accumulator zero-inits per
// wave/tile (~1365 VALU instrs/wave ~ 3 us/SIMD of issue on the binding VALU
// pipe) by holding a constant-zero Z in AGPRs and feeding it as cin to each
// chain's first MFMA (R26's pattern in R29's dual-chain slot). Regs: VGPR 84
// + AGPR 80 = 164 <= 170 cap at (256,3) -> no spill expected. Everything else
// identical to R29: 6 segs x 128 row-blocks = 768 blocks = 3 blocks/CU,
// 32 KB LDS dbuf, 2-chain column-pair interleave, segs 0-1 22 tiles / 2-5 21.
__global__ __launch_bounds__(256, 3) void sim_lse_kernel(
    const unsigned char* __restrict__ A, const unsigned char* __restrict__ B,
    float* __restrict__ lpart)
{
    __shared__ __align__(16) unsigned char bt[2 * TB];   // 2 x 16 KB double buffer

    int tid  = threadIdx.x;
    int lane = tid & 63;
    int l31  = lane & 31, half = lane >> 5;
    int wave = tid >> 6;
    int seg  = blockIdx.x;                        // 0..5
    int nt   = 21 + (seg < 2 ? 1 : 0);            // tiles this seg
    int T0   = seg * 21 + (seg < 2 ? seg : 2);    // first tile
    int rowBase = blockIdx.y * 128 + wave * 32;   // 32 rows per wave

    unsigned vb = (unsigned)(l31 * 16 + half * 1024);
    const int4 zero4 = make_int4(0, 0, 0, 0);

    // Preload A fragments (fp4, high half of 8-reg operand unused -> zeroed once)
    int8v af[4];
    {
        const unsigned char* ap = A + (size_t)(rowBase + l31) * DB + half * 16;
#pragma unroll
        for (int kk = 0; kk < 4; ++kk) {
            ((int4*)&af[kk])[0] = *(const int4*)(ap + kk * 32);
            ((int4*)&af[kk])[1] = zero4;
        }
    }

    f32x16 lv;
    f32x16 Z;                 // constant-zero cin (AGPR-resident; replaces per-unit inits)
    f32x16 p0, p1, q0, q1;    // two acc-pairs: compute one pair while exp-ing the other
#pragma unroll
    for (int r = 0; r < 16; ++r) {
        lv[r] = -2.0f;     // compensate the one dummy pair-epilogue (exp2(0)+exp2(0))
        Z[r]  = 0.0f;
        q0[r] = 0.0f; q1[r] = 0.0f;
    }

    auto stage = [&](int T, unsigned bufo) {
        const unsigned char* g = B + (size_t)T * TB + (unsigned)tid * 16;
        unsigned lo = bufo + (unsigned)tid * 16;
#pragma unroll
        for (int j = 0; j < 4; ++j) {
            __builtin_amdgcn_global_load_lds(
                (const __attribute__((address_space(1))) unsigned int*)(g + j * 4096),
                (__attribute__((address_space(3))) unsigned int*)&bt[lo + j * 4096],
                16, 0, 0);
        }
    };

#define MFMA4(dst, a, b, cin) \
    dst = __builtin_amdgcn_mfma_scale_f32_32x32x64_f8f6f4(a, b, cin, 4, 4, 0, SCA, 0, SCB)

    // One pair-slot: two independent depth-4 chains (cols at offA, offB) sharing af;
    // exps consume the other pair (e0,e1) fully (32 exp2+add), interleaved.
    // First MFMA of each chain takes Z as cin (no zero-init VALU pass).
    auto slot = [&](f32x16& c0, f32x16& c1, f32x16& e0, f32x16& e1,
                    unsigned ab, unsigned offA, unsigned offB) {
        int8v b0, b1, b2, b3;
        ((int4*)&b0)[1] = zero4; ((int4*)&b1)[1] = zero4;
        ((int4*)&b2)[1] = zero4; ((int4*)&b3)[1] = zero4;
        ((int4*)&b0)[0] = *(const int4*)&bt[ab + offA];            // chain0 kk=0
        ((int4*)&b1)[0] = *(const int4*)&bt[ab + offB];            // chain1 kk=0
        MFMA4(c0, af[0], b0, Z);
        MFMA4(c1, af[0], b1, Z);
#pragma unroll
        for (int r = 0; r < 8; ++r)  lv[r] += __builtin_amdgcn_exp2f(e0[r]);
        ((int4*)&b2)[0] = *(const int4*)&bt[ab + offA + 2048u];    // kk=1
        ((int4*)&b3)[0] = *(const int4*)&bt[ab + offB + 2048u];
        MFMA4(c0, af[1], b2, c0);
        MFMA4(c1, af[1], b3, c1);
#pragma unroll
        for (int r = 8; r < 16; ++r) lv[r] += __builtin_amdgcn_exp2f(e0[r]);
        ((int4*)&b0)[0] = *(const int4*)&bt[ab + offA + 4096u];    // kk=2
        ((int4*)&b1)[0] = *(const int4*)&bt[ab + offB + 4096u];
        MFMA4(c0, af[2], b0, c0);
        MFMA4(c1, af[2], b1, c1);
#pragma unroll
        for (int r = 0; r < 8; ++r)  lv[r] += __builtin_amdgcn_exp2f(e1[r]);
        ((int4*)&b2)[0] = *(const int4*)&bt[ab + offA + 6144u];    // kk=3
        ((int4*)&b3)[0] = *(const int4*)&bt[ab + offB + 6144u];
        MFMA4(c0, af[3], b2, c0);
        MFMA4(c1, af[3], b3, c1);
#pragma unroll
        for (int r = 8; r < 16; ++r) lv[r] += __builtin_amdgcn_exp2f(e1[r]);
    };

    stage(T0, 0);

    for (int t = 0; t < nt; ++t) {
        unsigned bufo = (t & 1) ? (unsigned)TB : 0u;
        __syncthreads();   // drains own tile-t DMA (in flight a full tile), syncs waves

        if (t + 1 < nt)
            stage(T0 + t + 1, (t & 1) ? 0u : (unsigned)TB);

        unsigned ab = vb + bufo;
        slot(p0, p1, q0, q1, ab, 0u,    512u);    // compute cols 0-63,  exp prev pair
        slot(q0, q1, p0, p1, ab, 8192u, 8704u);   // compute cols 64-127, exp pair just done
    }
    // final epilogue: exp the last computed pair (q0,q1)
#pragma unroll
    for (int r = 0; r < 16; ++r)
        lv[r] += __builtin_amdgcn_exp2f(q0[r]) + __builtin_amdgcn_exp2f(q1[r]);

    // Sum across the 32 column-lanes
#pragma unroll
    for (int r = 0; r < 16; ++r) {
        float v = lv[r];
        v += __shfl_xor(v, 1, 64);
        v += __shfl_xor(v, 2, 64);
        v += __shfl_xor(v, 4, 64);
        v += __shfl_xor(v, 8, 64);
        v += __shfl_xor(v, 16, 64);
        lv[r] = v;
    }
    if (l31 == 0) {
#pragma unroll
        for (int r = 0; r < 16; ++r) {
            int row = rowBase + (r & 3) + 8*(r >> 2) + 4*half;
            lpart[(size_t)seg * NROWS + row] = lv[r];
        }
    }
#undef MFMA4
}

// Kernel 3: loss_i = -invT*diag_i + ln2*log2(sum_seg l_part), then mean via atomicAdd.
__global__ __launch_bounds__(256) void reduce_kernel(
    const float* __restrict__ lpart, const float* __restrict__ diag,
    float* __restrict__ out)
{
    __shared__ float sm[4];
    int gtid = blockIdx.x * 256 + threadIdx.x;
    float s = 0.0f;
    for (int row = gtid; row < NROWS; row += 32 * 256) {
        float t = 0.0f;
#pragma unroll
        for (int g = 0; g < SEGS; ++g) t += lpart[(size_t)g * NROWS + row];
        s += LN2f * log2f(t) - INVT * diag[row];
    }
    for (int m = 1; m < 64; m <<= 1) s += __shfl_xor(s, m, 64);
    int wave = threadIdx.x >> 6, lane = threadIdx.x & 63;
    if (lane == 0) sm[wave] = s;
    __syncthreads();
    if (threadIdx.x == 0) {
        float tot = sm[0] + sm[1] + sm[2] + sm[3];
        atomicAdd(out, tot * (1.0f / NROWS));
    }
}

extern "C" void kernel_launch(void* const* d_in, const int* in_sizes, int n_in,
                              void* d_out, int out_size, void* d_ws, size_t ws_size,
                              hipStream_t stream) {
    const float* fl = (const float*)d_in[0];
    const float* fg = (const float*)d_in[1];
    float* out = (float*)d_out;

    char* ws = (char*)d_ws;
    unsigned char* A = (unsigned char*)ws;                         // 16384*128 = 2 MB (fp4)
    unsigned char* B = A + (size_t)NROWS * DB;                     // 2 MB (fp4, staging layout)
    float* diag  = (float*)(ws + 2 * (size_t)NROWS * DB);          // 64 KB
    float* lpart = diag + NROWS;                                   // SEGS*N*4 = 384 KB

    norm_diag_kernel<<<NROWS / 4, 256, 0, stream>>>(fl, fg, A, B, diag, out);
    sim_lse_kernel<<<dim3(SEGS, NROWS / 128), 256, 0, stream>>>(A, B, lpart);
    reduce_kernel<<<32, 256, 0, stream>>>(lpart, diag, out);
}

// Round 22
// 122.488 us; speedup vs baseline: 2.1480x; 1.0130x over previous
//
#include <hip/hip_runtime.h>
#include <hip/hip_bf16.h>

#define NROWS 16384
#define DIM   256
#define DB    (DIM / 2)               // 128 bytes per fp4 row
#define SEGS  6
#define BN    128                     // staged tile: 128 cols x 256 k (fp4) = 16 KB
#define TB    (BN * DB)               // 16384 bytes per staged tile
#define INVT  14.285714285714286f
#define C1f   20.60992915555662f      // log2(e)/0.07 ; A is pre-scaled by this
#define LN2f  0.6931471805599453f

typedef __attribute__((ext_vector_type(8)))  int   int8v;    // MFMA operand (fp4 uses low 4 regs)
typedef __attribute__((ext_vector_type(16))) float f32x16;   // 32x32 MFMA accumulator

#define SCA 0x7F7F7F7Fu   // E8M0 = 2^0   (A scale; A pre-scaled by C1, sigma~1.29)
#define SCB 0x7B7B7B7Bu   // E8M0 = 2^-4  (B scale; B pre-multiplied by 16, sigma~1.0)

// fp4 e2m1 RNE quantize: codes 0..7 = {0, .5, 1, 1.5, 2, 3, 4, 6} (monotonic), bit3 = sign
__device__ __forceinline__ unsigned fp4q(float v) {
    float a = fabsf(v);
    unsigned s = (__float_as_uint(v) >> 28) & 0x8u;
    unsigned idx = (unsigned)(a >= 0.25f) + (a >= 0.75f) + (a >= 1.25f) + (a >= 1.75f)
                 + (a >= 2.5f) + (a >= 3.5f) + (a >= 5.0f);
    return s | idx;
}

// Kernel 1: L2-normalize (fp32); emit fp4 A (row-major, xC1) and fp4 B (x16) in the
// DMA staging layout, plus exact fp32 diagonal. One wave per row.
__global__ __launch_bounds__(256) void norm_diag_kernel(
    const float* __restrict__ fl, const float* __restrict__ fg,
    unsigned char* __restrict__ A, unsigned char* __restrict__ B,
    float* __restrict__ diag, float* __restrict__ out)
{
    int tid  = threadIdx.x;
    int wave = tid >> 6, lane = tid & 63;
    int row  = blockIdx.x * 4 + wave;
    if (blockIdx.x == 0 && tid == 0) out[0] = 0.0f;   // zero accumulator for final atomicAdd

    float4 xl = ((const float4*)(fl + (size_t)row * DIM))[lane];
    float4 xg = ((const float4*)(fg + (size_t)row * DIM))[lane];
    float ssl = xl.x*xl.x + xl.y*xl.y + xl.z*xl.z + xl.w*xl.w;
    float ssg = xg.x*xg.x + xg.y*xg.y + xg.z*xg.z + xg.w*xg.w;
    for (int m = 1; m < 64; m <<= 1) {
        ssl += __shfl_xor(ssl, m, 64);
        ssg += __shfl_xor(ssg, m, 64);
    }
    float il = 1.0f / fmaxf(sqrtf(ssl), 1e-12f);
    float ig = 1.0f / fmaxf(sqrtf(ssg), 1e-12f);
    float nl0 = xl.x*il, nl1 = xl.y*il, nl2 = xl.z*il, nl3 = xl.w*il;
    float ng0 = xg.x*ig, ng1 = xg.y*ig, ng2 = xg.z*ig, ng3 = xg.w*ig;

    unsigned pa4 = fp4q(nl0 * C1f) | (fp4q(nl1 * C1f) << 4)
                 | (fp4q(nl2 * C1f) << 8) | (fp4q(nl3 * C1f) << 12);
    ((unsigned short*)(A + (size_t)row * DB))[lane] = (unsigned short)pa4;

    unsigned pb4 = fp4q(ng0 * 16.0f) | (fp4q(ng1 * 16.0f) << 4)
                 | (fp4q(ng2 * 16.0f) << 8) | (fp4q(ng3 * 16.0f) << 12);
    {
        int kcb4 = lane >> 3;         // 16B chunk along K (0..7)
        unsigned chunk = (unsigned)((row >> 7) * 1024 + ((row >> 6) & 1) * 512
                                    + kcb4 * 64 + (row & 63));
        ((unsigned short*)B)[chunk * 8 + (lane & 7)] = (unsigned short)pb4;
    }

    float d = nl0*ng0 + nl1*ng1 + nl2*ng2 + nl3*ng3;   // exact fp32 diagonal
    for (int m = 1; m < 64; m <<= 1) d += __shfl_xor(d, m, 64);
    if (lane == 0) diag[row] = d;
}

// Kernel 2: fused sim-GEMM + fixed-max sumexp, MX-fp4 32x32x64.
// R33 (resubmitted; broker timeouts) = R32 + T4 counted-vmcnt prefetch (the
// last catalog-proven lever vs the 50-us plateau). Ledger: 11 experiments
// (occupancy 2->3 waves, 1->2 chains, staging on/off/direct, SGB pins,
// zero-init removal) all land at 50+-1.5 us; MfmaUtil 26-27, VALUBusy 45-47,
// ~54% of cycles neither pipe issues -> stall-bound. The one structural
// element never removed: __syncthreads' full vmcnt(0) drain per tile (m97 asm:
// compiler emits s_waitcnt vmcnt(0) lgkmcnt(0) before s_barrier; m233: this
// 2-phase drain pattern costs ~72% in GEMM; m218: counted-vs-drain0 =
// +38-73%). This version: 3-deep LDS rotation (48 KB, 3 blocks/CU = 144 <=
// 160), prefetch 2 tiles ahead, and per tile the m201-template sequence:
// s_waitcnt vmcnt(4) [tile t done, t+1 stays in flight; vmcnt(0) only at the
// final tile] -> raw s_barrier -> sched_barrier(0) (rule-18 hoist guard) ->
// stage(t+2) -> compute(t). Race check: barrier t guarantees all waves
// finished compute(t-1) before stage(t+2) overwrites its buffer. Regs
// unchanged (~164, no spill at (256,3)).
__global__ __launch_bounds__(256, 3) void sim_lse_kernel(
    const unsigned char* __restrict__ A, const unsigned char* __restrict__ B,
    float* __restrict__ lpart)
{
    __shared__ __align__(16) unsigned char bt[3 * TB];   // 3 x 16 KB rotation

    int tid  = threadIdx.x;
    int lane = tid & 63;
    int l31  = lane & 31, half = lane >> 5;
    int wave = tid >> 6;
    int seg  = blockIdx.x;                        // 0..5
    int nt   = 21 + (seg < 2 ? 1 : 0);            // tiles this seg
    int T0   = seg * 21 + (seg < 2 ? seg : 2);    // first tile
    int rowBase = blockIdx.y * 128 + wave * 32;   // 32 rows per wave

    unsigned vb = (unsigned)(l31 * 16 + half * 1024);
    const int4 zero4 = make_int4(0, 0, 0, 0);

    // Preload A fragments (fp4, high half of 8-reg operand unused -> zeroed once)
    int8v af[4];
    {
        const unsigned char* ap = A + (size_t)(rowBase + l31) * DB + half * 16;
#pragma unroll
        for (int kk = 0; kk < 4; ++kk) {
            ((int4*)&af[kk])[0] = *(const int4*)(ap + kk * 32);
            ((int4*)&af[kk])[1] = zero4;
        }
    }

    f32x16 lv;
    f32x16 Z;                 // constant-zero cin (AGPR-resident)
    f32x16 p0, p1, q0, q1;    // two acc-pairs: compute one pair while exp-ing the other
#pragma unroll
    for (int r = 0; r < 16; ++r) {
        lv[r] = -2.0f;     // compensate the one dummy pair-epilogue (exp2(0)+exp2(0))
        Z[r]  = 0.0f;
        q0[r] = 0.0f; q1[r] = 0.0f;
    }

    auto stage = [&](int T, unsigned bufo) {
        const unsigned char* g = B + (size_t)T * TB + (unsigned)tid * 16;
        unsigned lo = bufo + (unsigned)tid * 16;
#pragma unroll
        for (int j = 0; j < 4; ++j) {
            __builtin_amdgcn_global_load_lds(
                (const __attribute__((address_space(1))) unsigned int*)(g + j * 4096),
                (__attribute__((address_space(3))) unsigned int*)&bt[lo + j * 4096],
                16, 0, 0);
        }
    };

#define MFMA4(dst, a, b, cin) \
    dst = __builtin_amdgcn_mfma_scale_f32_32x32x64_f8f6f4(a, b, cin, 4, 4, 0, SCA, 0, SCB)

    // One pair-slot: two independent depth-4 chains (cols at offA, offB) sharing af;
    // exps consume the other pair (e0,e1) fully (32 exp2+add), interleaved.
    auto slot = [&](f32x16& c0, f32x16& c1, f32x16& e0, f32x16& e1,
                    unsigned ab, unsigned offA, unsigned offB) {
        int8v b0, b1, b2, b3;
        ((int4*)&b0)[1] = zero4; ((int4*)&b1)[1] = zero4;
        ((int4*)&b2)[1] = zero4; ((int4*)&b3)[1] = zero4;
        ((int4*)&b0)[0] = *(const int4*)&bt[ab + offA];            // chain0 kk=0
        ((int4*)&b1)[0] = *(const int4*)&bt[ab + offB];            // chain1 kk=0
        MFMA4(c0, af[0], b0, Z);
        MFMA4(c1, af[0], b1, Z);
#pragma unroll
        for (int r = 0; r < 8; ++r)  lv[r] += __builtin_amdgcn_exp2f(e0[r]);
        ((int4*)&b2)[0] = *(const int4*)&bt[ab + offA + 2048u];    // kk=1
        ((int4*)&b3)[0] = *(const int4*)&bt[ab + offB + 2048u];
        MFMA4(c0, af[1], b2, c0);
        MFMA4(c1, af[1], b3, c1);
#pragma unroll
        for (int r = 8; r < 16; ++r) lv[r] += __builtin_amdgcn_exp2f(e0[r]);
        ((int4*)&b0)[0] = *(const int4*)&bt[ab + offA + 4096u];    // kk=2
        ((int4*)&b1)[0] = *(const int4*)&bt[ab + offB + 4096u];
        MFMA4(c0, af[2], b0, c0);
        MFMA4(c1, af[2], b1, c1);
#pragma unroll
        for (int r = 0; r < 8; ++r)  lv[r] += __builtin_amdgcn_exp2f(e1[r]);
        ((int4*)&b2)[0] = *(const int4*)&bt[ab + offA + 6144u];    // kk=3
        ((int4*)&b3)[0] = *(const int4*)&bt[ab + offB + 6144u];
        MFMA4(c0, af[3], b2, c0);
        MFMA4(c1, af[3], b3, c1);
#pragma unroll
        for (int r = 8; r < 16; ++r) lv[r] += __builtin_amdgcn_exp2f(e1[r]);
    };

    // Prologue: prefetch tiles 0 and 1 (8 loads/wave in flight)
    stage(T0, 0);
    stage(T0 + 1, TB);

    unsigned curo = 0;            // LDS offset of tile t
    unsigned stgo = 2u * TB;      // LDS offset for tile t+2

    for (int t = 0; t < nt; ++t) {
        // Counted wait: tile t's 4 loads complete; tile t+1's stay in flight.
        if (t + 1 < nt) {
            asm volatile("s_waitcnt vmcnt(4)" ::: "memory");
        } else {
            asm volatile("s_waitcnt vmcnt(0)" ::: "memory");
        }
        __builtin_amdgcn_s_barrier();
        __builtin_amdgcn_sched_barrier(0);   // keep ds_reads below the barrier

        if (t + 2 < nt)
            stage(T0 + t + 2, stgo);

        unsigned ab = vb + curo;
        slot(p0, p1, q0, q1, ab, 0u,    512u);    // compute cols 0-63,  exp prev pair
        slot(q0, q1, p0, p1, ab, 8192u, 8704u);   // compute cols 64-127, exp pair just done

        curo += TB; if (curo == 3u * TB) curo = 0;
        stgo += TB; if (stgo == 3u * TB) stgo = 0;
    }
    // final epilogue: exp the last computed pair (q0,q1)
#pragma unroll
    for (int r = 0; r < 16; ++r)
        lv[r] += __builtin_amdgcn_exp2f(q0[r]) + __builtin_amdgcn_exp2f(q1[r]);

    // Sum across the 32 column-lanes
#pragma unroll
    for (int r = 0; r < 16; ++r) {
        float v = lv[r];
        v += __shfl_xor(v, 1, 64);
        v += __shfl_xor(v, 2, 64);
        v += __shfl_xor(v, 4, 64);
        v += __shfl_xor(v, 8, 64);
        v += __shfl_xor(v, 16, 64);
        lv[r] = v;
    }
    if (l31 == 0) {
#pragma unroll
        for (int r = 0; r < 16; ++r) {
            int row = rowBase + (r & 3) + 8*(r >> 2) + 4*half;
            lpart[(size_t)seg * NROWS + row] = lv[r];
        }
    }
#undef MFMA4
}

// Kernel 3: loss_i = -invT*diag_i + ln2*log2(sum_seg l_part), then mean via atomicAdd.
__global__ __launch_bounds__(256) void reduce_kernel(
    const float* __restrict__ lpart, const float* __restrict__ diag,
    float* __restrict__ out)
{
    __shared__ float sm[4];
    int gtid = blockIdx.x * 256 + threadIdx.x;
    float s = 0.0f;
    for (int row = gtid; row < NROWS; row += 32 * 256) {
        float t = 0.0f;
#pragma unroll
        for (int g = 0; g < SEGS; ++g) t += lpart[(size_t)g * NROWS + row];
        s += LN2f * log2f(t) - INVT * diag[row];
    }
    for (int m = 1; m < 64; m <<= 1) s += __shfl_xor(s, m, 64);
    int wave = threadIdx.x >> 6, lane = threadIdx.x & 63;
    if (lane == 0) sm[wave] = s;
    __syncthreads();
    if (threadIdx.x == 0) {
        float tot = sm[0] + sm[1] + sm[2] + sm[3];
        atomicAdd(out, tot * (1.0f / NROWS));
    }
}

extern "C" void kernel_launch(void* const* d_in, const int* in_sizes, int n_in,
                              void* d_out, int out_size, void* d_ws, size_t ws_size,
                              hipStream_t stream) {
    const float* fl = (const float*)d_in[0];
    const float* fg = (const float*)d_in[1];
    float* out = (float*)d_out;

    char* ws = (char*)d_ws;
    unsigned char* A = (unsigned char*)ws;                         // 16384*128 = 2 MB (fp4)
    unsigned char* B = A + (size_t)NROWS * DB;                     // 2 MB (fp4, staging layout)
    float* diag  = (float*)(ws + 2 * (size_t)NROWS * DB);          // 64 KB
    float* lpart = diag + NROWS;                                   // SEGS*N*4 = 384 KB

    norm_diag_kernel<<<NROWS / 4, 256, 0, stream>>>(fl, fg, A, B, diag, out);
    sim_lse_kernel<<<dim3(SEGS, NROWS / 128), 256, 0, stream>>>(A, B, lpart);
    reduce_kernel<<<32, 256, 0, stream>>>(lpart, diag, out);
}